// Round 8
// baseline (285.566 us; speedup 1.0000x reference)
//
#include <hip/hip_runtime.h>
#include <float.h>
#include <math.h>

#define BATCH 8
#define CHN   128
#define NPTS  2048
#define KNN   9
#define NOUT  256
#define TOTCNT (BATCH*NPTS*KNN)

typedef __attribute__((ext_vector_type(8))) short short8;
typedef __attribute__((ext_vector_type(4))) float f32x4;

__device__ __forceinline__ unsigned short f2bf(float f) {
    unsigned int u = __float_as_uint(f);
    unsigned int r = (u + 0x7FFFu + ((u >> 16) & 1u)) >> 16;
    return (unsigned short)r;
}
__device__ __forceinline__ float bf2f(unsigned short h) {
    return __uint_as_float(((unsigned int)h) << 16);
}

// ---------------- kernel 1: transpose + bf16 split + 0.5*squared-norm ----------------
// grid (8 b, 32 ntile): blockIdx.x = b -> XCD pin
__global__ __launch_bounds__(256) void prep_kernel(const float* __restrict__ x,
                                                   unsigned short* __restrict__ xhi,
                                                   unsigned short* __restrict__ xlo,
                                                   float* __restrict__ sqh) {
    __shared__ float xt[128 * 65];
    __shared__ float psq[256];
    const int b = blockIdx.x, n0 = blockIdx.y * 64, tid = threadIdx.x;
#pragma unroll 4
    for (int p = 0; p < 32; ++p) {
        int c = p * 4 + (tid >> 6), n = tid & 63;
        xt[c * 65 + n] = x[((size_t)b * CHN + c) * NPTS + n0 + n];
    }
    __syncthreads();
    const int n = tid >> 2, cq = tid & 3;
    size_t row = (size_t)(b * NPTS + n0 + n) * CHN;
    float s = 0.f;
#pragma unroll 8
    for (int j = 0; j < 32; ++j) {
        int c = cq * 32 + j;
        float f = xt[c * 65 + n];
        unsigned short h = f2bf(f);
        float hf = bf2f(h);
        unsigned short l = f2bf(f - hf);
        xhi[row + c] = h;
        xlo[row + c] = l;
        s += f * f;
    }
    psq[tid] = s;
    __syncthreads();
    if (tid < 64)
        sqh[b * NPTS + n0 + tid] =
            0.5f * (psq[tid*4] + psq[tid*4+1] + psq[tid*4+2] + psq[tid*4+3]);
}

// ---------------- kernel 1b: W -> Bcat=[W1-W2; W2] bf16 hi/lo split ----------------
__global__ __launch_bounds__(256) void wprep_kernel(const float* __restrict__ W,
                                                    unsigned short* __restrict__ whi,
                                                    unsigned short* __restrict__ wlo) {
    int t = blockIdx.x * 256 + threadIdx.x;   // 0..16383
    int r = t >> 5, c0 = (t & 31) * 4;
#pragma unroll
    for (int e = 0; e < 4; ++e) {
        int c = c0 + e;
        float v = (r < 256) ? (W[r * 256 + c] - W[r * 256 + 128 + c])
                            : W[(r - 256) * 256 + 128 + c];
        unsigned short h = f2bf(v);
        float hf = bf2f(h);
        unsigned short l = f2bf(v - hf);
        whi[r * 128 + c] = h;
        wlo[r * 128 + c] = l;
    }
}

// ---------------- kernel 2: MFMA split-bf16 distance + top-9, BARRIER-FREE ----------------
// grid (8 b, 32 qtile, 4 mquarter) = 1024 blocks; blockIdx.x = b -> XCD pin.
// Each wave owns an independent 16q x 512m job with a wave-PRIVATE LDS dist tile:
// no __syncthreads anywhere -> no convoy stalls; same-wave LDS RAW is handled by
// compiler-inserted lgkmcnt. (R7: 8 barriers/block kept avg occupancy at 19% and
// dur at 89 us despite spill-free memory counters.)
__global__ __launch_bounds__(256) void knn_mfma(const unsigned short* __restrict__ xhi,
                                                const unsigned short* __restrict__ xlo,
                                                const float* __restrict__ sqh,
                                                float* __restrict__ pd,
                                                int* __restrict__ pi) {
    __shared__ __align__(16) float dts[4][16 * 132];   // 8448 B per wave, 33792 B total

    const int tid = threadIdx.x;
    const int b = blockIdx.x, q0 = blockIdx.y * 64, ms = blockIdx.z;
    const int wv = tid >> 6, lane = tid & 63;
    const int quad = lane >> 4, col = lane & 15;
    const int koff = quad * 8;
    const int qw = q0 + wv * 16;               // this wave's 16-query base
    const size_t xb = (size_t)b * NPTS * CHN;
    float* dtw = &dts[wv][0];

    float dl[KNN]; int il[KNN];
#pragma unroll
    for (int k = 0; k < KNN; ++k) { dl[k] = FLT_MAX; il[k] = 0; }

    const int qsc = lane >> 2, ss = lane & 3;  // scanner: 4 lanes per query (q-local 0..15)
    const int cb = ss * 32;

    auto ins = [&](float v, int idx) {
        if (v < dl[KNN - 1]) {
            bool c0b = v < dl[0];
#pragma unroll
            for (int k = KNN - 1; k >= 1; --k) {
                bool sh   = v < dl[k - 1];
                bool here = v < dl[k];
                float nd = sh ? dl[k - 1] : (here ? v : dl[k]);
                int   ni = sh ? il[k - 1] : (here ? idx : il[k]);
                dl[k] = nd; il[k] = ni;
            }
            if (c0b) { dl[0] = v; il[0] = idx; }
        }
    };

    // A-fragment row base is iter-invariant: row qw+col, k-seg koff
    const size_t ga0 = xb + (size_t)(qw + col) * CHN + koff;

    for (int iter = 0; iter < 4; ++iter) {
        const int mbase = ms * 512 + iter * 128;
        float sm[8];
#pragma unroll
        for (int j = 0; j < 8; ++j)
            sm[j] = sqh[b * NPTS + mbase + j * 16 + col];

        f32x4 acc[8];
#pragma unroll
        for (int j = 0; j < 8; ++j) acc[j] = (f32x4)0.f;

        for (int chk = 0; chk < 4; ++chk) {
            short8 ah = *(const short8*)&xhi[ga0 + chk * 32];
            short8 al = *(const short8*)&xlo[ga0 + chk * 32];
#pragma unroll
            for (int j = 0; j < 8; ++j) {
                size_t gb = xb + (size_t)(mbase + j * 16 + col) * CHN + chk * 32 + koff;
                short8 bh = *(const short8*)&xhi[gb];
                short8 bl = *(const short8*)&xlo[gb];
                acc[j] = __builtin_amdgcn_mfma_f32_16x16x32_bf16(ah, bh, acc[j], 0, 0, 0);
                acc[j] = __builtin_amdgcn_mfma_f32_16x16x32_bf16(ah, bl, acc[j], 0, 0, 0);
                acc[j] = __builtin_amdgcn_mfma_f32_16x16x32_bf16(al, bh, acc[j], 0, 0, 0);
            }
        }

        // dump wave-private 16q x 128m tile (no barrier; same-wave DS ordering)
#pragma unroll
        for (int j = 0; j < 8; ++j)
#pragma unroll
            for (int r = 0; r < 4; ++r) {
                int q_ = quad * 4 + r;
                dtw[q_ * 132 + j * 16 + col] = sm[j] - acc[j][r];
            }
        // scan: lane (qsc, ss) covers cols [ss*32, ss*32+32) of its query row
        const int ibase = mbase + cb;
#pragma unroll
        for (int jj = 0; jj < 8; ++jj) {
            float4 v = *(const float4*)&dtw[qsc * 132 + cb + jj * 4];
            float mn4 = fminf(fminf(v.x, v.y), fminf(v.z, v.w));
            if (mn4 < dl[KNN - 1]) {
                int ib = ibase + jj * 4;
                ins(v.x, ib); ins(v.y, ib + 1); ins(v.z, ib + 2); ins(v.w, ib + 3);
            }
        }
    }

    // wave-local merge of the 4 scanners' sorted lists per query
    float* md = dtw;                     // 16 x 36 floats
    int*   mi = (int*)(dtw + 16 * 36);   // 16 x 36 ints (both fit in 2112-float region)
#pragma unroll
    for (int k = 0; k < KNN; ++k) {
        md[qsc * 36 + ss * 9 + k] = dl[k];
        mi[qsc * 36 + ss * 9 + k] = il[k];
    }
    if (lane < 16) {
        int base = lane * 36;
        int p0 = 0, p1 = 0, p2 = 0, p3 = 0;
        size_t ob = ((size_t)(b * NPTS + qw + lane) * 4 + ms) * KNN;
        for (int k = 0; k < KNN; ++k) {
            float v0 = (p0 < KNN) ? md[base + p0]      : FLT_MAX;
            float v1 = (p1 < KNN) ? md[base + 9 + p1]  : FLT_MAX;
            float v2 = (p2 < KNN) ? md[base + 18 + p2] : FLT_MAX;
            float v3 = (p3 < KNN) ? md[base + 27 + p3] : FLT_MAX;
            float best = v0; int sel = 0;
            if (v1 < best) { best = v1; sel = 1; }
            if (v2 < best) { best = v2; sel = 2; }
            if (v3 < best) { best = v3; sel = 3; }
            int idx;
            if      (sel == 0) { idx = mi[base + p0];      p0++; }
            else if (sel == 1) { idx = mi[base + 9 + p1];  p1++; }
            else if (sel == 2) { idx = mi[base + 18 + p2]; p2++; }
            else               { idx = mi[base + 27 + p3]; p3++; }
            pd[ob + k] = best;
            pi[ob + k] = idx;
        }
    }
}

// ---------------- kernel 3: merge the four m-quarter top-9 lists ----------------
__global__ __launch_bounds__(256) void merge4_kernel(const float* __restrict__ pd,
                                                     const int* __restrict__ pi,
                                                     int* __restrict__ nn) {
    int q = blockIdx.x * 256 + threadIdx.x;   // 0..16383
    const float* d = pd + (size_t)q * 36;
    const int*   i = pi + (size_t)q * 36;
    int p0 = 0, p1 = 0, p2 = 0, p3 = 0;
#pragma unroll
    for (int k = 0; k < KNN; ++k) {
        float v0 = (p0 < KNN) ? d[p0]      : FLT_MAX;
        float v1 = (p1 < KNN) ? d[9 + p1]  : FLT_MAX;
        float v2 = (p2 < KNN) ? d[18 + p2] : FLT_MAX;
        float v3 = (p3 < KNN) ? d[27 + p3] : FLT_MAX;
        float best = v0; int sel = 0;
        if (v1 < best) { best = v1; sel = 1; }
        if (v2 < best) { best = v2; sel = 2; }
        if (v3 < best) { best = v3; sel = 3; }
        int idx;
        if      (sel == 0) { idx = i[p0];      p0++; }
        else if (sel == 1) { idx = i[9 + p1];  p1++; }
        else if (sel == 2) { idx = i[18 + p2]; p2++; }
        else               { idx = i[27 + p3]; p3++; }
        nn[q * KNN + k] = idx;
    }
}

// ---------------- kernel 4: p = x*(W1-W2)^T, q = x*W2^T via MFMA ----------------
// grid (8 b, 8 ntile-of-256, 8 otile-of-64); blockIdx.x = b -> XCD pin. No LDS, no barriers.
__global__ __launch_bounds__(256) void pq_mfma(const unsigned short* __restrict__ xhi,
                                               const unsigned short* __restrict__ xlo,
                                               const unsigned short* __restrict__ whi,
                                               const unsigned short* __restrict__ wlo,
                                               float* __restrict__ p,
                                               float* __restrict__ q) {
    const int tid = threadIdx.x;
    const int b = blockIdx.x, nt = blockIdx.y, ot = blockIdx.z;
    const int wv = tid >> 6, lane = tid & 63;
    const int quad = lane >> 4, col = lane & 15;
    const int koff = quad * 8;
    const size_t xb = (size_t)b * NPTS * CHN;
    const int nbase = nt * 256 + wv * 64;      // n within batch
    const int obase = ot * 64;                 // col in Bcat [512]

    f32x4 acc[4][4];
#pragma unroll
    for (int i = 0; i < 4; ++i)
#pragma unroll
        for (int j = 0; j < 4; ++j) acc[i][j] = (f32x4)0.f;

    for (int chk = 0; chk < 4; ++chk) {
        short8 ah[4], al[4];
#pragma unroll
        for (int i = 0; i < 4; ++i) {
            size_t g = xb + (size_t)(nbase + i * 16 + col) * CHN + chk * 32 + koff;
            ah[i] = *(const short8*)&xhi[g];
            al[i] = *(const short8*)&xlo[g];
        }
#pragma unroll
        for (int j = 0; j < 4; ++j) {
            size_t g = (size_t)(obase + j * 16 + col) * CHN + chk * 32 + koff;
            short8 bh = *(const short8*)&whi[g];
            short8 bl = *(const short8*)&wlo[g];
#pragma unroll
            for (int i = 0; i < 4; ++i) {
                acc[i][j] = __builtin_amdgcn_mfma_f32_16x16x32_bf16(ah[i], bh, acc[i][j], 0, 0, 0);
                acc[i][j] = __builtin_amdgcn_mfma_f32_16x16x32_bf16(ah[i], bl, acc[i][j], 0, 0, 0);
                acc[i][j] = __builtin_amdgcn_mfma_f32_16x16x32_bf16(al[i], bh, acc[i][j], 0, 0, 0);
            }
        }
    }
    float* dst = (ot < 4) ? p : q;
#pragma unroll
    for (int i = 0; i < 4; ++i)
#pragma unroll
        for (int j = 0; j < 4; ++j) {
            int oc = (obase + j * 16 + col) & 255;
#pragma unroll
            for (int r = 0; r < 4; ++r) {
                int n = nbase + i * 16 + quad * 4 + r;
                dst[(size_t)(b * NPTS + n) * NOUT + oc] = acc[i][j][r];
            }
        }
}

// ---------------- kernel 5: BN statistics + per-(n,o) max/min ----------------
// grid (8 b, 64 ntile-of-32); blockIdx.x = b -> XCD pin (q rows gathered from local L2).
__global__ __launch_bounds__(256) void stats2_kernel(float* __restrict__ p,
                                                     const float* __restrict__ q,
                                                     const int* __restrict__ nn,
                                                     float* __restrict__ stats,
                                                     float* __restrict__ hmn) {
    __shared__ int idx_s[32 * KNN];
    const int b = blockIdx.x, n0 = blockIdx.y * 32;
    const int o = threadIdx.x;
    for (int t = threadIdx.x; t < 32 * KNN; t += 256)
        idx_s[t] = nn[(size_t)(b * NPTS + n0) * KNN + t];
    __syncthreads();
    const float* qb = q + (size_t)b * NPTS * NOUT + o;
    float s = 0.f, ss = 0.f;
    for (int qq = 0; qq < 32; ++qq) {
        size_t off = (size_t)(b * NPTS + n0 + qq) * NOUT + o;
        float pv = p[off];
        float h[KNN];
#pragma unroll
        for (int k = 0; k < KNN; ++k)
            h[k] = pv + qb[(size_t)idx_s[qq * KNN + k] * NOUT];
        float mx = h[0], mn = h[0];
#pragma unroll
        for (int k = 0; k < KNN; ++k) {
            s += h[k]; ss += h[k] * h[k];
            mx = fmaxf(mx, h[k]); mn = fminf(mn, h[k]);
        }
        p[off] = mx;
        hmn[off] = mn;
    }
    atomicAdd(&stats[o], s);
    atomicAdd(&stats[NOUT + o], ss);
}

// ---------------- kernel 6: normalize + relu + max_k, transposed store ----------------
// grid (8 b, 128 ntile-of-16); blockIdx.x = b -> XCD pin.
__global__ __launch_bounds__(256) void final_kernel(const float* __restrict__ hmx,
                                                    const float* __restrict__ hmn,
                                                    const float* __restrict__ stats,
                                                    const float* __restrict__ gamma,
                                                    const float* __restrict__ beta,
                                                    float* __restrict__ out) {
    __shared__ float tr[256 * 17];
    const int b = blockIdx.x, n0 = blockIdx.y * 16;
    const int o = threadIdx.x;
    const float inv = 1.f / (float)TOTCNT;
    float mean = stats[o] * inv;
    float var  = stats[NOUT + o] * inv - mean * mean;
    float g    = gamma[o] / sqrtf(var + 1e-5f);
    float bet  = beta[o];
    for (int qq = 0; qq < 16; ++qq) {
        size_t off = (size_t)(b * NPTS + n0 + qq) * NOUT + o;
        float v = (g >= 0.f) ? hmx[off] : hmn[off];   // max of affine sits at hmax/hmin
        float hn = (v - mean) * g + bet;
        tr[o * 17 + qq] = fmaxf(hn, 0.f);
    }
    __syncthreads();
    int oo = threadIdx.x >> 4, qq = threadIdx.x & 15;
    for (int pass = 0; pass < 16; ++pass) {
        int o_ = pass * 16 + oo;
        out[((size_t)b * NOUT + o_) * NPTS + n0 + qq] = tr[o_ * 17 + qq];
    }
}

extern "C" void kernel_launch(void* const* d_in, const int* in_sizes, int n_in,
                              void* d_out, int out_size, void* d_ws, size_t ws_size,
                              hipStream_t stream) {
    (void)in_sizes; (void)n_in; (void)out_size; (void)ws_size;
    const float* x     = (const float*)d_in[0];
    const float* W     = (const float*)d_in[1];
    const float* gamma = (const float*)d_in[2];
    const float* beta  = (const float*)d_in[3];
    float* out = (float*)d_out;

    char* ws = (char*)d_ws;
    // [0,16M)  p  -> becomes hmax in stats2 (in-place)
    // [16,32M) q
    // [32,48M) knn/pq scratch (xhi,xlo,pd,pi,whi,wlo) -> dead by stats2, reused as hmn
    // [48M+)   sqh, stats, nn
    float*          p     = (float*)ws;
    float*          q     = (float*)(ws + (16u << 20));
    unsigned short* xhi   = (unsigned short*)(ws + (32u << 20));          // 4 MB
    unsigned short* xlo   = (unsigned short*)(ws + (36u << 20));          // 4 MB
    float*          pd    = (float*)(ws + (40u << 20));                   // 2.25 MB
    int*            pi    = (int*)  (ws + (43u << 20));                   // 2.25 MB
    unsigned short* whi   = (unsigned short*)(ws + (46u << 20));          // 128 KB
    unsigned short* wlo   = (unsigned short*)(ws + (46u << 20) + 131072); // 128 KB
    float*          hmn   = (float*)(ws + (32u << 20));                   // 16 MB overlay
    float*          sqh   = (float*)(ws + (48u << 20));                   // 64 KB
    float*          stats = (float*)(ws + (48u << 20) + 65536);           // 2 KB (pad 4K)
    int*            nn    = (int*)  (ws + (48u << 20) + 65536 + 4096);    // 576 KB

    hipMemsetAsync(stats, 0, 2 * NOUT * sizeof(float), stream);
    wprep_kernel <<<64,             256, 0, stream>>>(W, whi, wlo);
    prep_kernel  <<<dim3(8, 32),    256, 0, stream>>>(x, xhi, xlo, sqh);
    knn_mfma     <<<dim3(8, 32, 4), 256, 0, stream>>>(xhi, xlo, sqh, pd, pi);
    merge4_kernel<<<64,             256, 0, stream>>>(pd, pi, nn);
    pq_mfma      <<<dim3(8, 8, 8),  256, 0, stream>>>(xhi, xlo, whi, wlo, p, q);
    stats2_kernel<<<dim3(8, 64),    256, 0, stream>>>(p, q, nn, stats, hmn);
    final_kernel <<<dim3(8, 128),   256, 0, stream>>>(p, hmn, stats, gamma, beta, out);
}

// Round 9
// 220.466 us; speedup vs baseline: 1.2953x; 1.2953x over previous
//
#include <hip/hip_runtime.h>
#include <float.h>
#include <math.h>

#define BATCH 8
#define CHN   128
#define NPTS  2048
#define KNN   9
#define NOUT  256
#define TOTCNT (BATCH*NPTS*KNN)

typedef __attribute__((ext_vector_type(8))) short short8;
typedef __attribute__((ext_vector_type(4))) float f32x4;

__device__ __forceinline__ unsigned short f2bf(float f) {
    unsigned int u = __float_as_uint(f);
    unsigned int r = (u + 0x7FFFu + ((u >> 16) & 1u)) >> 16;
    return (unsigned short)r;
}
__device__ __forceinline__ float bf2f(unsigned short h) {
    return __uint_as_float(((unsigned int)h) << 16);
}

// ---------------- kernel 1: transpose + bf16 split + 0.5*squared-norm ----------------
// grid (8 b, 32 ntile): blockIdx.x = b -> XCD pin
__global__ __launch_bounds__(256) void prep_kernel(const float* __restrict__ x,
                                                   unsigned short* __restrict__ xhi,
                                                   unsigned short* __restrict__ xlo,
                                                   float* __restrict__ sqh) {
    __shared__ float xt[128 * 65];
    __shared__ float psq[256];
    const int b = blockIdx.x, n0 = blockIdx.y * 64, tid = threadIdx.x;
#pragma unroll 4
    for (int p = 0; p < 32; ++p) {
        int c = p * 4 + (tid >> 6), n = tid & 63;
        xt[c * 65 + n] = x[((size_t)b * CHN + c) * NPTS + n0 + n];
    }
    __syncthreads();
    const int n = tid >> 2, cq = tid & 3;
    size_t row = (size_t)(b * NPTS + n0 + n) * CHN;
    float s = 0.f;
#pragma unroll 8
    for (int j = 0; j < 32; ++j) {
        int c = cq * 32 + j;
        float f = xt[c * 65 + n];
        unsigned short h = f2bf(f);
        float hf = bf2f(h);
        unsigned short l = f2bf(f - hf);
        xhi[row + c] = h;
        xlo[row + c] = l;
        s += f * f;
    }
    psq[tid] = s;
    __syncthreads();
    if (tid < 64)
        sqh[b * NPTS + n0 + tid] =
            0.5f * (psq[tid*4] + psq[tid*4+1] + psq[tid*4+2] + psq[tid*4+3]);
}

// ---------------- kernel 1b: W -> Bcat=[W1-W2; W2] bf16 hi/lo split ----------------
__global__ __launch_bounds__(256) void wprep_kernel(const float* __restrict__ W,
                                                    unsigned short* __restrict__ whi,
                                                    unsigned short* __restrict__ wlo) {
    int t = blockIdx.x * 256 + threadIdx.x;   // 0..16383
    int r = t >> 5, c0 = (t & 31) * 4;
#pragma unroll
    for (int e = 0; e < 4; ++e) {
        int c = c0 + e;
        float v = (r < 256) ? (W[r * 256 + c] - W[r * 256 + 128 + c])
                            : W[(r - 256) * 256 + 128 + c];
        unsigned short h = f2bf(v);
        float hf = bf2f(h);
        unsigned short l = f2bf(v - hf);
        whi[r * 128 + c] = h;
        wlo[r * 128 + c] = l;
    }
}

// ---------------- kernel 2: MFMA split-bf16 distance + top-9 (R7 structure, 89us) ----------------
// grid (8 b, 32 qtile, 4 mquarter) = 1024 blocks; blockIdx.x = b -> XCD pin.
// 4 iters x 128-m tiles: per wave acc[4][2] (32 regs), dumped to LDS immediately
// after MFMA (acc never lives across a barrier -> no spill). R8's barrier-free
// variant regressed (1-A-frag reuse + VGPR 80 -> load-latency-bound); this
// 4-A-frag x 2-B-frag shape at VGPR ~120 is the measured best.
__global__ __launch_bounds__(256) void knn_mfma(const unsigned short* __restrict__ xhi,
                                                const unsigned short* __restrict__ xlo,
                                                const float* __restrict__ sqh,
                                                float* __restrict__ pd,
                                                int* __restrict__ pi) {
    __shared__ __align__(16) float dts[64 * 132];   // 33792 B

    const int tid = threadIdx.x;
    const int b = blockIdx.x, q0 = blockIdx.y * 64, ms = blockIdx.z;
    const int msbase = ms * 512;
    const int wv = tid >> 6, lane = tid & 63;
    const int quad = lane >> 4, col = lane & 15;
    const int koff = quad * 8;
    const int mcol0 = wv * 32;                      // this wave's col base in the 128-tile
    const size_t xb = (size_t)b * NPTS * CHN;

    float dl[KNN]; int il[KNN];
#pragma unroll
    for (int k = 0; k < KNN; ++k) { dl[k] = FLT_MAX; il[k] = 0; }

    const int qsc = tid >> 2, ss = tid & 3;   // scanner: 4 threads per query
    const int cb = ss * 32;

    auto ins = [&](float v, int idx) {
        if (v < dl[KNN - 1]) {
            bool c0b = v < dl[0];
#pragma unroll
            for (int k = KNN - 1; k >= 1; --k) {
                bool sh   = v < dl[k - 1];
                bool here = v < dl[k];
                float nd = sh ? dl[k - 1] : (here ? v : dl[k]);
                int   ni = sh ? il[k - 1] : (here ? idx : il[k]);
                dl[k] = nd; il[k] = ni;
            }
            if (c0b) { dl[0] = v; il[0] = idx; }
        }
    };

    for (int iter = 0; iter < 4; ++iter) {
        const int mbase = msbase + iter * 128;
        float sm[2];
#pragma unroll
        for (int j = 0; j < 2; ++j)
            sm[j] = sqh[b * NPTS + mbase + mcol0 + j * 16 + col];

        f32x4 acc[4][2];
#pragma unroll
        for (int i = 0; i < 4; ++i)
#pragma unroll
            for (int j = 0; j < 2; ++j) acc[i][j] = (f32x4)0.f;

        for (int chk = 0; chk < 4; ++chk) {
            short8 ah[4], al[4];
#pragma unroll
            for (int i = 0; i < 4; ++i) {
                size_t g = xb + (size_t)(q0 + i * 16 + col) * CHN + chk * 32 + koff;
                ah[i] = *(const short8*)&xhi[g];
                al[i] = *(const short8*)&xlo[g];
            }
#pragma unroll
            for (int j = 0; j < 2; ++j) {
                size_t g = xb + (size_t)(mbase + mcol0 + j * 16 + col) * CHN + chk * 32 + koff;
                short8 bh = *(const short8*)&xhi[g];
                short8 bl = *(const short8*)&xlo[g];
#pragma unroll
                for (int i = 0; i < 4; ++i) {
                    acc[i][j] = __builtin_amdgcn_mfma_f32_16x16x32_bf16(ah[i], bh, acc[i][j], 0, 0, 0);
                    acc[i][j] = __builtin_amdgcn_mfma_f32_16x16x32_bf16(ah[i], bl, acc[i][j], 0, 0, 0);
                    acc[i][j] = __builtin_amdgcn_mfma_f32_16x16x32_bf16(al[i], bh, acc[i][j], 0, 0, 0);
                }
            }
        }

        __syncthreads();   // previous scan done with dts
        // dump whole 64q x 128m tile (each wave its 32 cols); acc dead after this
#pragma unroll
        for (int j = 0; j < 2; ++j)
#pragma unroll
            for (int i = 0; i < 4; ++i)
#pragma unroll
                for (int r = 0; r < 4; ++r) {
                    int q_ = i * 16 + quad * 4 + r;
                    dts[q_ * 132 + mcol0 + j * 16 + col] = sm[j] - acc[i][j][r];
                }
        __syncthreads();
        // scan: scanner ss covers cols [ss*32, ss*32+32)
        const int ibase = mbase + cb;
#pragma unroll
        for (int jj = 0; jj < 8; ++jj) {
            float4 v = *(const float4*)&dts[qsc * 132 + cb + jj * 4];
            float mn4 = fminf(fminf(v.x, v.y), fminf(v.z, v.w));
            if (mn4 < dl[KNN - 1]) {
                int ib = ibase + jj * 4;
                ins(v.x, ib); ins(v.y, ib + 1); ins(v.z, ib + 2); ins(v.w, ib + 3);
            }
        }
    }

    // merge the 4 scanners' sorted lists per query; emit per-quarter top-9 with dists
    __syncthreads();
    float* md = dts;                    // 64 x 36 floats
    int*   mi = (int*)(dts + 2304);     // 64 x 36 ints
#pragma unroll
    for (int k = 0; k < KNN; ++k) {
        md[qsc * 36 + ss * 9 + k] = dl[k];
        mi[qsc * 36 + ss * 9 + k] = il[k];
    }
    __syncthreads();
    if (tid < 64) {
        int base = tid * 36;
        int p0 = 0, p1 = 0, p2 = 0, p3 = 0;
        size_t ob = ((size_t)(b * NPTS + q0 + tid) * 4 + ms) * KNN;
        for (int k = 0; k < KNN; ++k) {
            float v0 = (p0 < KNN) ? md[base + p0]      : FLT_MAX;
            float v1 = (p1 < KNN) ? md[base + 9 + p1]  : FLT_MAX;
            float v2 = (p2 < KNN) ? md[base + 18 + p2] : FLT_MAX;
            float v3 = (p3 < KNN) ? md[base + 27 + p3] : FLT_MAX;
            float best = v0; int sel = 0;
            if (v1 < best) { best = v1; sel = 1; }
            if (v2 < best) { best = v2; sel = 2; }
            if (v3 < best) { best = v3; sel = 3; }
            int idx;
            if      (sel == 0) { idx = mi[base + p0];      p0++; }
            else if (sel == 1) { idx = mi[base + 9 + p1];  p1++; }
            else if (sel == 2) { idx = mi[base + 18 + p2]; p2++; }
            else               { idx = mi[base + 27 + p3]; p3++; }
            pd[ob + k] = best;
            pi[ob + k] = idx;
        }
    }
}

// ---------------- kernel 3: p = x*(W1-W2)^T, q = x*W2^T via MFMA ----------------
// grid (8 b, 8 ntile-of-256, 8 otile-of-64); blockIdx.x = b -> XCD pin. No LDS, no barriers.
__global__ __launch_bounds__(256) void pq_mfma(const unsigned short* __restrict__ xhi,
                                               const unsigned short* __restrict__ xlo,
                                               const unsigned short* __restrict__ whi,
                                               const unsigned short* __restrict__ wlo,
                                               float* __restrict__ p,
                                               float* __restrict__ q) {
    const int tid = threadIdx.x;
    const int b = blockIdx.x, nt = blockIdx.y, ot = blockIdx.z;
    const int wv = tid >> 6, lane = tid & 63;
    const int quad = lane >> 4, col = lane & 15;
    const int koff = quad * 8;
    const size_t xb = (size_t)b * NPTS * CHN;
    const int nbase = nt * 256 + wv * 64;      // n within batch
    const int obase = ot * 64;                 // col in Bcat [512]

    f32x4 acc[4][4];
#pragma unroll
    for (int i = 0; i < 4; ++i)
#pragma unroll
        for (int j = 0; j < 4; ++j) acc[i][j] = (f32x4)0.f;

    for (int chk = 0; chk < 4; ++chk) {
        short8 ah[4], al[4];
#pragma unroll
        for (int i = 0; i < 4; ++i) {
            size_t g = xb + (size_t)(nbase + i * 16 + col) * CHN + chk * 32 + koff;
            ah[i] = *(const short8*)&xhi[g];
            al[i] = *(const short8*)&xlo[g];
        }
#pragma unroll
        for (int j = 0; j < 4; ++j) {
            size_t g = (size_t)(obase + j * 16 + col) * CHN + chk * 32 + koff;
            short8 bh = *(const short8*)&whi[g];
            short8 bl = *(const short8*)&wlo[g];
#pragma unroll
            for (int i = 0; i < 4; ++i) {
                acc[i][j] = __builtin_amdgcn_mfma_f32_16x16x32_bf16(ah[i], bh, acc[i][j], 0, 0, 0);
                acc[i][j] = __builtin_amdgcn_mfma_f32_16x16x32_bf16(ah[i], bl, acc[i][j], 0, 0, 0);
                acc[i][j] = __builtin_amdgcn_mfma_f32_16x16x32_bf16(al[i], bh, acc[i][j], 0, 0, 0);
            }
        }
    }
    float* dst = (ot < 4) ? p : q;
#pragma unroll
    for (int i = 0; i < 4; ++i)
#pragma unroll
        for (int j = 0; j < 4; ++j) {
            int oc = (obase + j * 16 + col) & 255;
#pragma unroll
            for (int r = 0; r < 4; ++r) {
                int n = nbase + i * 16 + quad * 4 + r;
                dst[(size_t)(b * NPTS + n) * NOUT + oc] = acc[i][j][r];
            }
        }
}

// ---------------- kernel 4: merge4 FUSED + BN statistics + per-(n,o) max/min ----------------
// grid (8 b, 64 ntile-of-32); blockIdx.x = b -> XCD pin.
// Threads 0..31 merge their query's four sorted top-9 lists (pd/pi) in-block,
// then all 256 threads gather. merge4_kernel dispatch + nn round-trip removed.
__global__ __launch_bounds__(256) void stats2_kernel(float* __restrict__ p,
                                                     const float* __restrict__ q,
                                                     const float* __restrict__ pd,
                                                     const int* __restrict__ pi,
                                                     float* __restrict__ stats,
                                                     float* __restrict__ hmn) {
    __shared__ int idx_s[32 * KNN];
    const int b = blockIdx.x, n0 = blockIdx.y * 32;
    const int o = threadIdx.x;
    if (threadIdx.x < 32) {
        size_t g = (size_t)(b * NPTS + n0 + threadIdx.x) * 36;
        const float* d = pd + g;
        const int*   i = pi + g;
        int p0 = 0, p1 = 0, p2 = 0, p3 = 0;
#pragma unroll
        for (int k = 0; k < KNN; ++k) {
            float v0 = (p0 < KNN) ? d[p0]      : FLT_MAX;
            float v1 = (p1 < KNN) ? d[9 + p1]  : FLT_MAX;
            float v2 = (p2 < KNN) ? d[18 + p2] : FLT_MAX;
            float v3 = (p3 < KNN) ? d[27 + p3] : FLT_MAX;
            float best = v0; int sel = 0;
            if (v1 < best) { best = v1; sel = 1; }
            if (v2 < best) { best = v2; sel = 2; }
            if (v3 < best) { best = v3; sel = 3; }
            int idx;
            if      (sel == 0) { idx = i[p0];      p0++; }
            else if (sel == 1) { idx = i[9 + p1];  p1++; }
            else if (sel == 2) { idx = i[18 + p2]; p2++; }
            else               { idx = i[27 + p3]; p3++; }
            idx_s[threadIdx.x * KNN + k] = idx;
        }
    }
    __syncthreads();
    const float* qb = q + (size_t)b * NPTS * NOUT + o;
    float s = 0.f, ss = 0.f;
    for (int qq = 0; qq < 32; ++qq) {
        size_t off = (size_t)(b * NPTS + n0 + qq) * NOUT + o;
        float pv = p[off];
        float h[KNN];
#pragma unroll
        for (int k = 0; k < KNN; ++k)
            h[k] = pv + qb[(size_t)idx_s[qq * KNN + k] * NOUT];
        float mx = h[0], mn = h[0];
#pragma unroll
        for (int k = 0; k < KNN; ++k) {
            s += h[k]; ss += h[k] * h[k];
            mx = fmaxf(mx, h[k]); mn = fminf(mn, h[k]);
        }
        p[off] = mx;
        hmn[off] = mn;
    }
    atomicAdd(&stats[o], s);
    atomicAdd(&stats[NOUT + o], ss);
}

// ---------------- kernel 5: normalize + relu + max_k, transposed store ----------------
// grid (8 b, 128 ntile-of-16); blockIdx.x = b -> XCD pin.
// Pointer-select BEFORE the load: reads 16 MB (one of hmx/hmn), not 32.
__global__ __launch_bounds__(256) void final_kernel(const float* __restrict__ hmx,
                                                    const float* __restrict__ hmn,
                                                    const float* __restrict__ stats,
                                                    const float* __restrict__ gamma,
                                                    const float* __restrict__ beta,
                                                    float* __restrict__ out) {
    __shared__ float tr[256 * 17];
    const int b = blockIdx.x, n0 = blockIdx.y * 16;
    const int o = threadIdx.x;
    const float inv = 1.f / (float)TOTCNT;
    float mean = stats[o] * inv;
    float var  = stats[NOUT + o] * inv - mean * mean;
    float g    = gamma[o] / sqrtf(var + 1e-5f);
    float bet  = beta[o];
    const float* src = (g >= 0.f) ? hmx : hmn;   // max of affine sits at hmax/hmin
    for (int qq = 0; qq < 16; ++qq) {
        size_t off = (size_t)(b * NPTS + n0 + qq) * NOUT + o;
        float hn = (src[off] - mean) * g + bet;
        tr[o * 17 + qq] = fmaxf(hn, 0.f);
    }
    __syncthreads();
    int oo = threadIdx.x >> 4, qq = threadIdx.x & 15;
    for (int pass = 0; pass < 16; ++pass) {
        int o_ = pass * 16 + oo;
        out[((size_t)b * NOUT + o_) * NPTS + n0 + qq] = tr[o_ * 17 + qq];
    }
}

extern "C" void kernel_launch(void* const* d_in, const int* in_sizes, int n_in,
                              void* d_out, int out_size, void* d_ws, size_t ws_size,
                              hipStream_t stream) {
    (void)in_sizes; (void)n_in; (void)out_size; (void)ws_size;
    const float* x     = (const float*)d_in[0];
    const float* W     = (const float*)d_in[1];
    const float* gamma = (const float*)d_in[2];
    const float* beta  = (const float*)d_in[3];
    float* out = (float*)d_out;

    char* ws = (char*)d_ws;
    // [0,16M)  p  -> becomes hmax in stats2 (in-place)
    // [16,32M) q
    // [32,48M) knn/pq scratch (xhi,xlo,whi,wlo) -> dead by stats2, reused as hmn
    // [48M+)   pd, pi (live into stats2), sqh, stats
    float*          p     = (float*)ws;
    float*          q     = (float*)(ws + (16u << 20));
    unsigned short* xhi   = (unsigned short*)(ws + (32u << 20));          // 4 MB
    unsigned short* xlo   = (unsigned short*)(ws + (36u << 20));          // 4 MB
    unsigned short* whi   = (unsigned short*)(ws + (40u << 20));          // 128 KB
    unsigned short* wlo   = (unsigned short*)(ws + (40u << 20) + 131072); // 128 KB
    float*          hmn   = (float*)(ws + (32u << 20));                   // 16 MB overlay
    float*          pd    = (float*)(ws + (48u << 20));                   // 2.25 MB
    int*            pi    = (int*)  (ws + (51u << 20));                   // 2.25 MB
    float*          sqh   = (float*)(ws + (54u << 20));                   // 64 KB
    float*          stats = (float*)(ws + (54u << 20) + 65536);           // 2 KB

    hipMemsetAsync(stats, 0, 2 * NOUT * sizeof(float), stream);
    wprep_kernel <<<64,             256, 0, stream>>>(W, whi, wlo);
    prep_kernel  <<<dim3(8, 32),    256, 0, stream>>>(x, xhi, xlo, sqh);
    knn_mfma     <<<dim3(8, 32, 4), 256, 0, stream>>>(xhi, xlo, sqh, pd, pi);
    pq_mfma      <<<dim3(8, 8, 8),  256, 0, stream>>>(xhi, xlo, whi, wlo, p, q);
    stats2_kernel<<<dim3(8, 64),    256, 0, stream>>>(p, q, pd, pi, stats, hmn);
    final_kernel <<<dim3(8, 128),   256, 0, stream>>>(p, hmn, stats, gamma, beta, out);
}